// Round 1
// baseline (260.249 us; speedup 1.0000x reference)
//
#include <hip/hip_runtime.h>

constexpr int TN = 8192;   // tokens
constexpr int DN = 4096;   // model dim
constexpr int EN = 64;     // experts

constexpr int ROWS = 64;   // rows per block (lane = row)
constexpr int NW   = 4;    // waves per block
constexpr int KC   = 32;   // d-chunk staged per step
constexpr int PSTR = 65;   // padded LDS row stride (floats)

// Kernel 1: partial logits. Grid = 128 row-tiles * NSPLIT d-splits.
// Each wave owns a (DN/NSPLIT/NW)-wide d-slice; lane = row (64 rows/block).
// wg is read via wave-uniform addresses -> scalar loads (SGPR), FMA with
// s-operand; x staged coalesced into transposed padded LDS.
template <int NSPLIT>
__global__ __launch_bounds__(256, 2)
void gate_partial_kernel(const float* __restrict__ x,
                         const float* __restrict__ wg,
                         float* __restrict__ part_out)  // [NSPLIT][TN][EN]
{
    constexpr int DBLK  = DN / NSPLIT;   // d per block
    constexpr int DWAVE = DBLK / NW;     // d per wave
    constexpr int NC    = DWAVE / KC;    // chunks per wave

    const int b    = blockIdx.x;
    const int rt   = b / NSPLIT;
    const int dsp  = b % NSPLIT;
    const int r0   = rt * ROWS;
    const int tid  = threadIdx.x;
    const int w    = __builtin_amdgcn_readfirstlane(tid >> 6);  // wave-uniform
    const int lane = tid & 63;

    __shared__ float lds[NW * ROWS * PSTR];  // 16640 floats; staging uses first 8320

    float* xs = &lds[w * (KC * PSTR)];       // per-wave staging [KC][PSTR]

    const int dbase = dsp * DBLK + w * DWAVE;   // wave-uniform
    const float* wgd = wg + dbase;              // wave-uniform pointer

    float acc[EN];
#pragma unroll
    for (int e = 0; e < EN; ++e) acc[e] = 0.0f;

    const int rsub = lane >> 3;  // 0..7
    const int jsub = lane & 7;   // 0..7

    float4 pv[8], nv[8];
    // prefetch chunk 0 (coalesced: 8 lanes x float4 = 128B per row, 8 rows/iter)
#pragma unroll
    for (int i = 0; i < 8; ++i) {
        const int row = i * 8 + rsub;
        pv[i] = *reinterpret_cast<const float4*>(
            &x[(size_t)(r0 + row) * DN + dbase + jsub * 4]);
    }

    for (int c = 0; c < NC; ++c) {
        // stage chunk c into LDS, transposed [k][row] (2-way bank alias = free)
#pragma unroll
        for (int i = 0; i < 8; ++i) {
            const int row = i * 8 + rsub;
            xs[(jsub * 4 + 0) * PSTR + row] = pv[i].x;
            xs[(jsub * 4 + 1) * PSTR + row] = pv[i].y;
            xs[(jsub * 4 + 2) * PSTR + row] = pv[i].z;
            xs[(jsub * 4 + 3) * PSTR + row] = pv[i].w;
        }
        // prefetch chunk c+1 (global latency hides under the FMA block)
        if (c + 1 < NC) {
#pragma unroll
            for (int i = 0; i < 8; ++i) {
                const int row = i * 8 + rsub;
                nv[i] = *reinterpret_cast<const float4*>(
                    &x[(size_t)(r0 + row) * DN + dbase + (c + 1) * KC + jsub * 4]);
            }
        }
        // own row's chunk from LDS (consecutive addrs per k -> conflict-free)
        float xv[KC];
#pragma unroll
        for (int k = 0; k < KC; ++k) xv[k] = xs[k * PSTR + lane];

        const float* wc = wgd + c * KC;  // wave-uniform
#pragma unroll
        for (int e = 0; e < EN; ++e) {
            const float* wr = wc + (size_t)e * DN;  // uniform -> s_load
            float cs = xv[0] * wr[0];
#pragma unroll
            for (int k = 1; k < KC; ++k) cs = fmaf(xv[k], wr[k], cs);
            acc[e] += cs;  // two-level sum: keeps fp32 error ~2e-6
        }
#pragma unroll
        for (int i = 0; i < 8; ++i) pv[i] = nv[i];
    }

    // cross-wave reduce via LDS: part[w][row][e]
    __syncthreads();
    float* part = lds;
#pragma unroll
    for (int e = 0; e < EN; ++e)
        part[w * (ROWS * PSTR) + lane * PSTR + e] = acc[e];
    __syncthreads();

    {
        const int row = tid >> 2;  // 0..63
        const int seg = tid & 3;   // 16 experts each
        const float* po = part + row * PSTR + seg * 16;
        float res[16];
#pragma unroll
        for (int j = 0; j < 16; ++j) {
            res[j] = po[j]
                   + po[1 * ROWS * PSTR + j]
                   + po[2 * ROWS * PSTR + j]
                   + po[3 * ROWS * PSTR + j];
        }
        float* dst = part_out + (size_t)dsp * TN * EN
                              + (size_t)(r0 + row) * EN + seg * 16;
#pragma unroll
        for (int j = 0; j < 16; j += 4) {
            float4 v = make_float4(res[j], res[j + 1], res[j + 2], res[j + 3]);
            *reinterpret_cast<float4*>(&dst[j]) = v;
        }
    }
}

// Kernel 2: sum NSPLIT partials, top-1 softmax per row.
// out[0..TN) = argmax index (as float), out[TN..2TN) = max gate = 1/sumexp.
template <int NSPLIT>
__global__ __launch_bounds__(256)
void top1_softmax_kernel(const float* __restrict__ part, float* __restrict__ out)
{
    const int row = blockIdx.x * blockDim.x + threadIdx.x;
    if (row >= TN) return;

    float v[EN];
#pragma unroll
    for (int i = 0; i < EN / 4; ++i) {
        float4 s = *reinterpret_cast<const float4*>(
            &part[(size_t)row * EN + i * 4]);
#pragma unroll
        for (int h = 1; h < NSPLIT; ++h) {
            float4 t = *reinterpret_cast<const float4*>(
                &part[((size_t)h * TN + row) * EN + i * 4]);
            s.x += t.x; s.y += t.y; s.z += t.z; s.w += t.w;
        }
        v[i * 4 + 0] = s.x; v[i * 4 + 1] = s.y;
        v[i * 4 + 2] = s.z; v[i * 4 + 3] = s.w;
    }

    float m = v[0];
    int idx = 0;
#pragma unroll
    for (int e = 1; e < EN; ++e) {
        if (v[e] > m) { m = v[e]; idx = e; }  // strict > : first occurrence, matches jnp.argmax
    }
    float s = 0.0f;
#pragma unroll
    for (int e = 0; e < EN; ++e) s += __expf(v[e] - m);

    out[row]      = (float)idx;
    out[TN + row] = 1.0f / s;
}

extern "C" void kernel_launch(void* const* d_in, const int* in_sizes, int n_in,
                              void* d_out, int out_size, void* d_ws, size_t ws_size,
                              hipStream_t stream) {
    const float* x  = (const float*)d_in[0];
    const float* wg = (const float*)d_in[1];
    float* out  = (float*)d_out;
    float* part = (float*)d_ws;

    const size_t need4 = (size_t)4 * TN * EN * sizeof(float);  // 8 MB
    if (ws_size >= need4) {
        gate_partial_kernel<4><<<dim3(128 * 4), dim3(256), 0, stream>>>(x, wg, part);
        top1_softmax_kernel<4><<<dim3(TN / 256), dim3(256), 0, stream>>>(part, out);
    } else if (ws_size >= need4 / 2) {
        gate_partial_kernel<2><<<dim3(128 * 2), dim3(256), 0, stream>>>(x, wg, part);
        top1_softmax_kernel<2><<<dim3(TN / 256), dim3(256), 0, stream>>>(part, out);
    } else {
        gate_partial_kernel<1><<<dim3(128), dim3(256), 0, stream>>>(x, wg, part);
        top1_softmax_kernel<1><<<dim3(TN / 256), dim3(256), 0, stream>>>(part, out);
    }
}

// Round 2
// 93.893 us; speedup vs baseline: 2.7718x; 2.7718x over previous
//
#include <hip/hip_runtime.h>

constexpr int TN = 8192;   // tokens
constexpr int DN = 4096;   // model dim
constexpr int EN = 64;     // experts

constexpr int MB  = 64;    // rows per block
constexpr int KB  = 32;    // k per step
constexpr int KBP = 36;    // padded x row stride (floats, 144B -> 16B aligned)

// Kernel 1: register-blocked fp32 GEMM. Grid = 128 row-tiles * KSPLIT k-splits.
// 256 threads, thread tile 4x4 (rows x experts). Both operands staged in
// double-buffered LDS, read as ds_read_b128 along K. part[ks][row][e] to ws.
template <int KSPLIT>
__global__ __launch_bounds__(256, 2)
void gate_gemm_kernel(const float* __restrict__ x,
                      const float* __restrict__ wg,
                      float* __restrict__ part)
{
    constexpr int KBLK = DN / KSPLIT;  // k per block
    constexpr int NT   = KBLK / KB;    // k-steps

    const int bid = blockIdx.x;
    const int rt  = bid / KSPLIT;
    const int ks  = bid % KSPLIT;
    const int r0  = rt * MB;
    const int k0  = ks * KBLK;
    const int tid = threadIdx.x;

    // x tile: [row][k] padded; wg tile: re-blocked [kk][n][cg][j] so that the
    // 16 col-groups' b128 reads are contiguous 256B (2-way bank alias = free).
    __shared__ __align__(16) float xl[2][MB][KBP];          // 2 * 9216 B
    __shared__ __align__(16) float wl[2][KB / 4][4][16][4]; // 2 * 8192 B

    // staging mapping: 8 lanes per row (128B contiguous per row segment)
    const int srow = tid >> 3;   // 0..31 (x row; +32 second half)
    const int skseg = tid & 7;   // float4 index within 32-wide k chunk
    const int se   = tid >> 3;   // 0..31 (wg expert; +32 second half)
    const int skk  = tid & 7;    // k4-group for wg

    // compute mapping: cg = expert group (4 experts), rg = row group (4 rows)
    const int cg = tid & 15;
    const int rg = tid >> 4;

    float acc[4][4] = {};
    float4 xr0, xr1, wr0, wr1;

    auto g_load = [&](int t) {
        const int kt = k0 + t * KB;
        xr0 = *reinterpret_cast<const float4*>(&x[(size_t)(r0 + srow) * DN + kt + skseg * 4]);
        xr1 = *reinterpret_cast<const float4*>(&x[(size_t)(r0 + srow + 32) * DN + kt + skseg * 4]);
        wr0 = *reinterpret_cast<const float4*>(&wg[(size_t)se * DN + kt + skk * 4]);
        wr1 = *reinterpret_cast<const float4*>(&wg[(size_t)(se + 32) * DN + kt + skk * 4]);
    };
    auto l_store = [&](int b) {
        *reinterpret_cast<float4*>(&xl[b][srow][skseg * 4])      = xr0;
        *reinterpret_cast<float4*>(&xl[b][srow + 32][skseg * 4]) = xr1;
        *reinterpret_cast<float4*>(&wl[b][skk][se & 3][se >> 2][0])        = wr0;
        *reinterpret_cast<float4*>(&wl[b][skk][se & 3][(se >> 2) + 8][0])  = wr1;
    };
    auto compute = [&](int b) {
#pragma unroll
        for (int kk = 0; kk < KB / 4; ++kk) {
            float4 xf[4], wf[4];
#pragma unroll
            for (int m = 0; m < 4; ++m)  // 16-lane broadcast, 2 bank-quads: free
                xf[m] = *reinterpret_cast<const float4*>(&xl[b][rg * 4 + m][kk * 4]);
#pragma unroll
            for (int n = 0; n < 4; ++n)  // contiguous 256B across cg: free
                wf[n] = *reinterpret_cast<const float4*>(&wl[b][kk][n][cg][0]);
#pragma unroll
            for (int m = 0; m < 4; ++m)
#pragma unroll
                for (int n = 0; n < 4; ++n) {
                    acc[m][n] = fmaf(xf[m].x, wf[n].x, acc[m][n]);
                    acc[m][n] = fmaf(xf[m].y, wf[n].y, acc[m][n]);
                    acc[m][n] = fmaf(xf[m].z, wf[n].z, acc[m][n]);
                    acc[m][n] = fmaf(xf[m].w, wf[n].w, acc[m][n]);
                }
        }
    };

    g_load(0);
    l_store(0);
    __syncthreads();
    int cur = 0;
    for (int t = 0; t < NT; ++t) {
        if (t + 1 < NT) g_load(t + 1);   // issue early: latency hides under FMAs
        compute(cur);
        if (t + 1 < NT) {
            l_store(cur ^ 1);            // write other buffer: no extra barrier
            __syncthreads();
            cur ^= 1;
        }
    }

    // write partials: [ks][row][64], float4 per m, 16 cg lanes contiguous 256B
    float* dst = part + ((size_t)ks * TN + (size_t)(r0 + rg * 4)) * EN + cg * 4;
#pragma unroll
    for (int m = 0; m < 4; ++m) {
        *reinterpret_cast<float4*>(&dst[(size_t)m * EN]) =
            make_float4(acc[m][0], acc[m][1], acc[m][2], acc[m][3]);
    }
}

// Kernel 2: sum KSPLIT partials, top-1 softmax per row.
// out[0..TN) = argmax index (as float), out[TN..2TN) = max gate = 1/sumexp.
template <int NSPLIT>
__global__ __launch_bounds__(256)
void top1_softmax_kernel(const float* __restrict__ part, float* __restrict__ out)
{
    const int row = blockIdx.x * blockDim.x + threadIdx.x;
    if (row >= TN) return;

    float v[EN];
#pragma unroll
    for (int i = 0; i < EN / 4; ++i) {
        float4 s = *reinterpret_cast<const float4*>(&part[(size_t)row * EN + i * 4]);
#pragma unroll
        for (int h = 1; h < NSPLIT; ++h) {
            float4 t = *reinterpret_cast<const float4*>(
                &part[((size_t)h * TN + row) * EN + i * 4]);
            s.x += t.x; s.y += t.y; s.z += t.z; s.w += t.w;
        }
        v[i * 4 + 0] = s.x; v[i * 4 + 1] = s.y;
        v[i * 4 + 2] = s.z; v[i * 4 + 3] = s.w;
    }

    float m = v[0];
    int idx = 0;
#pragma unroll
    for (int e = 1; e < EN; ++e) {
        if (v[e] > m) { m = v[e]; idx = e; }  // strict >: first occurrence = jnp.argmax
    }
    float s = 0.0f;
#pragma unroll
    for (int e = 0; e < EN; ++e) s += __expf(v[e] - m);

    out[row]      = (float)idx;
    out[TN + row] = 1.0f / s;
}

extern "C" void kernel_launch(void* const* d_in, const int* in_sizes, int n_in,
                              void* d_out, int out_size, void* d_ws, size_t ws_size,
                              hipStream_t stream) {
    const float* x  = (const float*)d_in[0];
    const float* wg = (const float*)d_in[1];
    float* out  = (float*)d_out;
    float* part = (float*)d_ws;

    const size_t need4 = (size_t)4 * TN * EN * sizeof(float);  // 8 MB
    if (ws_size >= need4) {
        gate_gemm_kernel<4><<<dim3(128 * 4), dim3(256), 0, stream>>>(x, wg, part);
        top1_softmax_kernel<4><<<dim3(TN / 256), dim3(256), 0, stream>>>(part, out);
    } else if (ws_size >= need4 / 2) {
        gate_gemm_kernel<2><<<dim3(128 * 2), dim3(256), 0, stream>>>(x, wg, part);
        top1_softmax_kernel<2><<<dim3(TN / 256), dim3(256), 0, stream>>>(part, out);
    } else {
        gate_gemm_kernel<1><<<dim3(128), dim3(256), 0, stream>>>(x, wg, part);
        top1_softmax_kernel<1><<<dim3(TN / 256), dim3(256), 0, stream>>>(part, out);
    }
}